// Round 14
// baseline (4398.747 us; speedup 1.0000x reference)
//
#include <hip/hip_runtime.h>
#include <hip/hip_bf16.h>

typedef __bf16 bf16x8 __attribute__((ext_vector_type(8)));
typedef float f32x4 __attribute__((ext_vector_type(4)));
typedef unsigned int uint4v __attribute__((ext_vector_type(4)));
typedef unsigned short ushortT;
typedef ushortT ushort8v __attribute__((ext_vector_type(8)));

__device__ __forceinline__ ushortT f2b(float f) {
    __bf16 b = (__bf16)f;
    return __builtin_bit_cast(ushortT, b);
}

// bijective chunked XCD swizzle (m204)
__device__ __forceinline__ unsigned xcd_swz(unsigned bx, unsigned nwg) {
    unsigned q = nwg >> 3, r = nwg & 7, xcd = bx & 7, off = bx >> 3;
    return (xcd < r ? xcd * (q + 1) : r * (q + 1) + (xcd - r) * q) + off;
}

// ---------------- input pack: fp32 [16][7][64^3] -> halo-padded bf16 ----------
__global__ __launch_bounds__(256) void pack_x(const float* __restrict__ x,
                                              ushortT* __restrict__ xb)
{
    long e = (long)blockIdx.x * 256 + threadIdx.x;   // 16*72^3 = 5,971,968
    if (e >= 5971968L) return;
    int wp_ = (int)(e % 72); long r = e / 72;
    int hp = (int)(r % 72); r /= 72;
    int dp = (int)(r % 72); int b = (int)(r / 72);
    ushort8v v = (ushort8v)0;
    int dd = dp - 4, hh = hp - 4, ww = wp_ - 4;
    if ((unsigned)dd < 64u && (unsigned)hh < 64u && (unsigned)ww < 64u) {
        int sp = (dd * 64 + hh) * 64 + ww;
        #pragma unroll
        for (int c = 0; c < 7; ++c)
            v[c] = f2b(x[((size_t)(b * 7 + c)) * 262144 + sp]);
    }
    *(ushort8v*)(xb + e * 8) = v;
}

// ---------------- weight pack (conv_ig layout): [NBY][KSTEPS][4][NW][8] -------
__global__ void pack_w(const float* __restrict__ W, ushortT* __restrict__ wp,
                       int Cin, int CINP, int Cout, int NW, int KSTEPS, int total)
{
    int e = blockIdx.x * 256 + threadIdx.x;
    if (e >= total) return;
    int j = e & 7;
    int r = e >> 3;
    int c = r % NW; r /= NW;
    int q = r & 3; r >>= 2;
    int s = r % KSTEPS;
    int nby = r / KSTEPS;
    int k = s * 32 + q * 8 + j;
    int tap = k / CINP;
    int ci = k - tap * CINP;
    int n = nby * NW + c;
    float v = 0.f;
    if (tap < 125 && ci < Cin && n < Cout)
        v = W[((size_t)n * Cin + ci) * 125 + tap];
    wp[e] = f2b(v);
}

// ---- weight pack (conv_lds2 layout): [NBY][CHUNKS][32 s][4 q][NW][8 j] ------
// k-mapping: tap = 4s + q; ci = c*8 + j
__global__ void pack_w_lds2(const float* __restrict__ W, ushortT* __restrict__ wp,
                            int Cin, int Cout, int NW, int CHUNKS, int total)
{
    int e = blockIdx.x * 256 + threadIdx.x;
    if (e >= total) return;
    int j = e & 7;
    int r = e >> 3;
    int n = r % NW; r /= NW;
    int q = r & 3; r >>= 2;
    int s = r % 32; r /= 32;
    int c = r % CHUNKS;
    int nby = r / CHUNKS;
    int tap = 4 * s + q;
    int ci = c * 8 + j;
    int nn = nby * NW + n;
    float v = 0.f;
    if (tap < 125 && ci < Cin && nn < Cout)
        v = W[((size_t)nn * Cin + ci) * 125 + tap];
    wp[e] = f2b(v);
}

// ---------------- implicit-GEMM conv, direct global A (stride-2 stages) ------
template<int CINP, int INDP, int OUTD, int STRIDE, int COUT, int NFRAG, int KSTEPS, int KTOT>
__global__ __launch_bounds__(256)
void conv_ig(const ushortT* __restrict__ xcl, const ushortT* __restrict__ wp,
             float* __restrict__ y)
{
    constexpr int S3 = OUTD * OUTD * OUTD;
    constexpr long MTOT = 16L * S3;
    constexpr int NW = NFRAG * 16;
    const int t = threadIdx.x, lane = t & 63, wave = t >> 6;
    const unsigned bx = xcd_swz(blockIdx.x, gridDim.x);
    const long mbase = (long)bx * 256 + wave * 64;
    const int slot = lane >> 4;

    unsigned rb[4];
    #pragma unroll
    for (int i = 0; i < 4; ++i) {
        long m = mbase + i * 16 + (lane & 15);
        if (m >= MTOT) m = MTOT - 1;
        int b = (int)(m / S3); int sp = (int)(m % S3);
        int od = sp / (OUTD * OUTD); int oh = (sp / OUTD) % OUTD; int ow = sp % OUTD;
        rb[i] = (unsigned)(((((b * INDP) + od * STRIDE) * INDP + oh * STRIDE) * INDP
                            + ow * STRIDE) * CINP);
    }
    const ushortT* wptr = wp + ((size_t)((blockIdx.y * KSTEPS) * 4 + slot) * NW
                                + (lane & 15)) * 8;

    f32x4 acc[NFRAG][4];
    #pragma unroll
    for (int n = 0; n < NFRAG; ++n)
        #pragma unroll
        for (int i = 0; i < 4; ++i) acc[n][i] = (f32x4)0.f;

    for (int s = 0; s < KSTEPS; ++s) {
        const int k0 = s * 32 + slot * 8;
        const int tap = k0 / CINP;
        const int ci = k0 - tap * CINP;
        const int kd = tap / 25;
        const int rr = tap - kd * 25;
        const int kh = rr / 5;
        const int kw = rr - kh * 5;
        const unsigned toff = (unsigned)(((kd * INDP + kh) * INDP + kw) * CINP + ci);
        const bool valid = k0 < KTOT;
        uint4v a[4];
        #pragma unroll
        for (int i = 0; i < 4; ++i) {
            unsigned idx = valid ? (rb[i] + toff) : 0u;
            a[i] = *(const uint4v*)(xcl + idx);
        }
        uint4v bv[NFRAG];
        #pragma unroll
        for (int n = 0; n < NFRAG; ++n)
            bv[n] = *(const uint4v*)(wptr + (size_t)s * (4 * NW * 8) + n * 128);
        #pragma unroll
        for (int n = 0; n < NFRAG; ++n) {
            bf16x8 bb = __builtin_bit_cast(bf16x8, bv[n]);
            #pragma unroll
            for (int i = 0; i < 4; ++i)
                acc[n][i] = __builtin_amdgcn_mfma_f32_16x16x32_bf16(
                    __builtin_bit_cast(bf16x8, a[i]), bb, acc[n][i], 0, 0, 0);
        }
    }

    const int rbase = (lane >> 4) * 4;
    #pragma unroll
    for (int n = 0; n < NFRAG; ++n) {
        int nn = blockIdx.y * NW + n * 16 + (lane & 15);
        if (nn >= COUT) continue;
        #pragma unroll
        for (int i = 0; i < 4; ++i) {
            #pragma unroll
            for (int r = 0; r < 4; ++r) {
                long mm = mbase + i * 16 + rbase + r;
                if (mm < MTOT) y[(size_t)mm * COUT + nn] = acc[n][i][r];
            }
        }
    }
}

// --------- LDS-patch implicit-GEMM conv v2: 8-ch chunks for occupancy --------
// patch layout [pos][8ch] = 16B/pos; K-step = 4 taps x 8 ch; 32 steps/chunk.
// r10-r13 lessons: keep this loop structure exactly (no unroll of the 32-step
// loop, no setprio, no cross-barrier prefetch, no addr-precompute arrays).
// r14 change (ONLY): tofftab LDS table -> exact magic-mul arithmetic, freeing
// 512 B so the s8 patch (20480 B) fits 8 blocks/CU (was 7 + serialized tail).
template<int CHUNKS, int INDP, int OUTD, int TD, int TH, int COUT, int NFRAG, int MFRAG>
__global__ __launch_bounds__(256)
void conv_lds2(const ushortT* __restrict__ xcl, const ushortT* __restrict__ wp,
               float* __restrict__ y)
{
    constexpr int CH = CHUNKS * 8;
    constexpr int PD = TD + 4, PH = TH + 4, PW = INDP;
    constexpr int P3 = PD * PH * PW;
    constexpr int ROWS = TD * TH * OUTD;
    constexpr int NW = NFRAG * 16;
    constexpr int NTD = (OUTD + TD - 1) / TD;
    constexpr int NTH = (OUTD + TH - 1) / TH;
    constexpr size_t PERNBY = (size_t)CHUNKS * 32 * 4 * NW * 8;
    static_assert(ROWS <= MFRAG * 64, "row coverage");

    __shared__ __align__(16) ushortT patch[P3 * 8];

    const int t = threadIdx.x, lane = t & 63, wave = t >> 6;
    const unsigned bt = xcd_swz(blockIdx.x, gridDim.x);
    const int img = bt / (NTD * NTH);
    const int t2 = bt % (NTD * NTH);
    const int od0 = (t2 / NTH) * TD;
    const int oh0 = (t2 % NTH) * TH;

    const int r16 = lane & 15, q = lane >> 4;

    int rb[MFRAG];
    #pragma unroll
    for (int i = 0; i < MFRAG; ++i) {
        int r = wave * (MFRAG * 16) + i * 16 + r16;
        if (r >= ROWS) r = ROWS - 1;
        int td = r / (TH * OUTD); int rem = r - td * (TH * OUTD);
        int th = rem / OUTD; int ow = rem - th * OUTD;
        rb[i] = (td * PH + th) * PW + ow;
    }

    const ushortT* wb = wp + (size_t)blockIdx.y * PERNBY + ((size_t)q * NW + r16) * 8;
    const ushortT* src0 = xcl + (size_t)img * INDP * INDP * INDP * CH;

    f32x4 acc[NFRAG][MFRAG];
    #pragma unroll
    for (int n = 0; n < NFRAG; ++n)
        #pragma unroll
        for (int i = 0; i < MFRAG; ++i) acc[n][i] = (f32x4)0.f;

    for (int c = 0; c < CHUNKS; ++c) {
        __syncthreads();                      // prior chunk's patch reads done
        for (int u = t; u < P3; u += 256) {
            int pd = u / (PH * PW); int pr = u - pd * (PH * PW);
            int ph = pr / PW; int pw = pr - ph * PW;
            int gd = od0 + pd; if (gd > INDP - 1) gd = INDP - 1;
            int gh = oh0 + ph; if (gh > INDP - 1) gh = INDP - 1;
            const ushortT* sp_ = src0 + (((size_t)gd * INDP + gh) * INDP + pw) * CH
                                 + c * 8;
            uint4v v = *(const uint4v*)sp_;
            *(uint4v*)&patch[u * 8] = v;
        }
        __syncthreads();                      // patch ready
        const ushortT* wc = wb + (size_t)c * (32 * 4 * NW * 8);
        for (int s = 0; s < 32; ++s) {
            // tap offset via exact magic-mul (verified over tap in [0,124]);
            // pad taps (>=125, zero weights) clamp to 0
            int tap = 4 * s + q;
            int tapc = tap < 125 ? tap : 0;
            int kd = (tapc * 41) >> 10;       // /25
            int rr = tapc - kd * 25;
            int kh = (rr * 13) >> 6;          // /5
            int kw = rr - kh * 5;
            int toffv = (kd * PH + kh) * PW + kw;
            uint4v bv[NFRAG];
            #pragma unroll
            for (int n = 0; n < NFRAG; ++n)
                bv[n] = *(const uint4v*)(wc + (size_t)s * (4 * NW * 8) + n * 128);
            #pragma unroll
            for (int i = 0; i < MFRAG; ++i) {
                bf16x8 av = *(const bf16x8*)&patch[(rb[i] + toffv) * 8];
                #pragma unroll
                for (int n = 0; n < NFRAG; ++n)
                    acc[n][i] = __builtin_amdgcn_mfma_f32_16x16x32_bf16(
                        av, __builtin_bit_cast(bf16x8, bv[n]), acc[n][i], 0, 0, 0);
            }
        }
    }

    // epilogue: D map col = r16 (n), row = q*4 + reg (m within 16)
    #pragma unroll
    for (int i = 0; i < MFRAG; ++i) {
        #pragma unroll
        for (int vr = 0; vr < 4; ++vr) {
            int r = wave * (MFRAG * 16) + i * 16 + q * 4 + vr;
            if (r >= ROWS) continue;
            int td = r / (TH * OUTD); int rem = r - td * (TH * OUTD);
            int th = rem / OUTD; int ow = rem - th * OUTD;
            int od = od0 + td, oh = oh0 + th;
            if (od >= OUTD || oh >= OUTD) continue;
            size_t row = ((size_t)img * OUTD + od) * (size_t)(OUTD * OUTD)
                       + (size_t)oh * OUTD + ow;
            #pragma unroll
            for (int n = 0; n < NFRAG; ++n) {
                int nn = blockIdx.y * NW + n * 16 + r16;
                if (nn < COUT) y[row * COUT + nn] = acc[n][i][vr];
            }
        }
    }
}

// ---------------- BN partial sums over y [rows][C], C<=256 ----------------
__global__ __launch_bounds__(256)
void bn_partial_cl(const float* __restrict__ y, float* __restrict__ part,
                   long rows, int C, int crlog2)
{
    const int t = threadIdx.x;
    const int CR = 1 << crlog2;
    const int c = t & (CR - 1);
    const int r0 = t >> crlog2;
    const int rstep = 256 >> crlog2;
    float s0 = 0.f, q0 = 0.f;
    const bool has = c < C;
    for (long r = (long)blockIdx.x * rstep + r0; r < rows; r += 256L * rstep) {
        if (has) { float v = y[(size_t)r * C + c]; s0 += v; q0 = fmaf(v, v, q0); }
    }
    __shared__ float l0[256], l1[256];
    l0[t] = s0; l1[t] = q0; __syncthreads();
    if (t < CR) {
        for (int j = 1; j < rstep; ++j) { s0 += l0[t + j * CR]; q0 += l1[t + j * CR]; }
        if (t < C) {
            part[((size_t)blockIdx.x * 256 + t) * 2]     = s0;
            part[((size_t)blockIdx.x * 256 + t) * 2 + 1] = q0;
        }
    }
}

__global__ void bn_finalize(const float* __restrict__ part, float* __restrict__ stats,
                            int C, float invN)
{
    int c = threadIdx.x;
    if (c >= C) return;
    float s = 0.f, q = 0.f;
    for (int k = 0; k < 256; ++k) {
        s += part[((size_t)k * 256 + c) * 2];
        q += part[((size_t)k * 256 + c) * 2 + 1];
    }
    float mean = s * invN;
    float var = q * invN - mean * mean;
    stats[2 * c] = mean;
    stats[2 * c + 1] = rsqrtf(var + 1e-5f);
}

// ---------------- BN for C=512 (stage 8), y [rows][512] ----------------
__global__ __launch_bounds__(256)
void bn_partial512(const float* __restrict__ y, float* __restrict__ part, long rows)
{
    const int t = threadIdx.x;
    float s0 = 0.f, q0 = 0.f, s1 = 0.f, q1 = 0.f;
    for (long r = blockIdx.x; r < rows; r += 256) {
        const float* row = y + (size_t)r * 512;
        float v0 = row[t];       s0 += v0; q0 = fmaf(v0, v0, q0);
        float v1 = row[t + 256]; s1 += v1; q1 = fmaf(v1, v1, q1);
    }
    part[((size_t)blockIdx.x * 512 + t) * 2]           = s0;
    part[((size_t)blockIdx.x * 512 + t) * 2 + 1]       = q0;
    part[((size_t)blockIdx.x * 512 + t + 256) * 2]     = s1;
    part[((size_t)blockIdx.x * 512 + t + 256) * 2 + 1] = q1;
}

__global__ void bn_finalize512(const float* __restrict__ part, float* __restrict__ stats,
                               float invN)
{
    int c = blockIdx.x * 256 + threadIdx.x;   // grid 2 x 256
    float s = 0.f, q = 0.f;
    for (int k = 0; k < 256; ++k) {
        s += part[((size_t)k * 512 + c) * 2];
        q += part[((size_t)k * 512 + c) * 2 + 1];
    }
    float mean = s * invN;
    float var = q * invN - mean * mean;
    stats[2 * c] = mean;
    stats[2 * c + 1] = rsqrtf(var + 1e-5f);
}

// ---------------- normalize + gate -> halo-padded bf16 for next stage --------
template<int CINP, int INDP, int OUTD>
__global__ __launch_bounds__(256)
void act_pad(const float* __restrict__ y, const float* __restrict__ stats,
             ushortT* __restrict__ h, int COUT, int d, int m0, int m1)
{
    constexpr long TOT = 16L * INDP * INDP * INDP * CINP;
    long e = (long)blockIdx.x * 256 + threadIdx.x;
    if (e >= TOT) return;
    int c = (int)(e % CINP); long r = e / CINP;
    int wp_ = (int)(r % INDP); r /= INDP;
    int hp = (int)(r % INDP); r /= INDP;
    int dp = (int)(r % INDP); int b = (int)(r / INDP);
    float o = 0.f;
    int dd = dp - 4, hh = hp - 4, ww = wp_ - 4;
    if (c < d && (unsigned)dd < (unsigned)OUTD && (unsigned)hh < (unsigned)OUTD
        && (unsigned)ww < (unsigned)OUTD) {
        long row = ((b * (long)OUTD + dd) * OUTD + hh) * OUTD + ww;
        float v = (y[row * COUT + c] - stats[2 * c]) * stats[2 * c + 1];
        if (c < m0) {
            o = fmaxf(v, 0.f);
        } else {
            int gi = (c < m0 + 3 * m1) ? (d + (c - m0) / 3)
                                       : (d + m1 + (c - m0 - 3 * m1) / 5);
            float g = (y[row * COUT + gi] - stats[2 * gi]) * stats[2 * gi + 1];
            o = v / (1.f + __expf(-g));
        }
    }
    h[e] = f2b(o);
}

// ---------------- stage-8 pooling over y [16][4096][512] ----------------
__global__ __launch_bounds__(256)
void pool_partial512(const float* __restrict__ y, const float* __restrict__ stats,
                     float* __restrict__ pp)
{
    const int b = blockIdx.x, slab = blockIdx.y, t = threadIdx.x;
    const int c0 = t, c1 = t + 256;
    const float mu0 = stats[2 * c0], iv0 = stats[2 * c0 + 1];
    const float mu1 = stats[2 * c1], iv1 = stats[2 * c1 + 1];
    float a0 = 0.f, a1 = 0.f;
    for (int i = 0; i < 64; ++i) {
        const float* row = y + ((size_t)b * 4096 + slab * 64 + i) * 512;
        a0 += fmaxf((row[c0] - mu0) * iv0, 0.f);
        a1 += fmaxf((row[c1] - mu1) * iv1, 0.f);
    }
    pp[(size_t)(b * 64 + slab) * 512 + c0] = a0;
    pp[(size_t)(b * 64 + slab) * 512 + c1] = a1;
}

__global__ void pool_final512(const float* __restrict__ pp, float* __restrict__ pooled)
{
    const int b = blockIdx.x, t = threadIdx.x;
    float a0 = 0.f, a1 = 0.f;
    for (int s = 0; s < 64; ++s) {
        a0 += pp[(size_t)(b * 64 + s) * 512 + t];
        a1 += pp[(size_t)(b * 64 + s) * 512 + t + 256];
    }
    pooled[b * 512 + t]       = a0 * (1.f / 4096.f);
    pooled[b * 512 + t + 256] = a1 * (1.f / 4096.f);
}

// ---------------- final linear ----------------
__global__ void linear20(const float* __restrict__ pooled, const float* __restrict__ lw,
                         const float* __restrict__ lb, float* __restrict__ out)
{
    const int n = blockIdx.x, b = blockIdx.y;
    const float* p = pooled + b * 512;
    const float* w = lw + n * 512;
    float s = 0.f;
    for (int c = threadIdx.x; c < 512; c += 64) s = fmaf(p[c], w[c], s);
    for (int o = 32; o > 0; o >>= 1) s += __shfl_down(s, o);
    if (threadIdx.x == 0) out[b * 20 + n] = s + lb[n];
}

// ---------------- host ----------------
extern "C" void kernel_launch(void* const* d_in, const int* in_sizes, int n_in,
                              void* d_out, int out_size, void* d_ws, size_t ws_size,
                              hipStream_t stream) {
    const float* x = (const float*)d_in[0];
    const float* Wf[8];
    for (int i = 0; i < 8; ++i) Wf[i] = (const float*)d_in[1 + i];
    const float* linW = (const float*)d_in[9];
    const float* linb = (const float*)d_in[10];
    float* out = (float*)d_out;
    float* ws = (float*)d_ws;

    // workspace layout (float units)
    const size_t OFF_Y    = 0;            // 33,554,432 f (max y: s8 65536x512)
    const size_t OFF_H    = 33554432;     // 23,887,872 f (bf16)
    const size_t OFF_WP   = 57442304;     //  6,326,016 f (bf16)
    const size_t OFF_PART = 63768320;     //    262,144 f
    const size_t OFF_PP   = 64030464;     //    524,288 f
    const size_t OFF_ST   = 64554752;     //      1,024 f
    const size_t OFF_PL   = 64555776;     //      8,192 f
    const size_t NEEDF    = 64563968;     // ~258.3 MB
    if (ws_size < NEEDF * sizeof(float)) return;

    float* yb = ws + OFF_Y;
    ushortT* H = (ushortT*)(ws + OFF_H);
    ushortT* wpb = (ushortT*)(ws + OFF_WP);
    float* part = ws + OFF_PART;
    float* pp = ws + OFF_PP;
    float* stats = ws + OFF_ST;
    float* pooled = ws + OFF_PL;

    // packed-weight offsets (ushort units)
    const size_t WPO_S1 = 0;          // ig:   32*4*32*8       = 32,768
    const size_t WPO_S3 = 32768;      // ig:   94*4*64*8       = 192,512
    const size_t WPO_S5 = 225280;     // ig:   2*188*4*64*8    = 770,048
    const size_t WPO_S7 = 995328;     // ig:   3*375*4*48*8    = 1,728,000
    const size_t WPO_S2 = 2723328;    // lds2: 1*3*32*4*32*8   = 98,304
    const size_t WPO_S4 = 2821632;    // lds2: 1*6*32*4*64*8   = 393,216
    const size_t WPO_S6 = 3214848;    // lds2: 2*12*32*4*64*8  = 1,572,864
    const size_t WPO_S8 = 4787712;    // lds2: 8*15*32*4*64*8  = 7,864,320

    pack_x<<<23328, 256, 0, stream>>>(x, H);
    pack_w<<<(32768 + 255) / 256, 256, 0, stream>>>(Wf[0], wpb + WPO_S1, 7, 8, 24, 32, 32, 32768);
    pack_w<<<(192512 + 255) / 256, 256, 0, stream>>>(Wf[2], wpb + WPO_S3, 20, 24, 56, 64, 94, 192512);
    pack_w<<<(770048 + 255) / 256, 256, 0, stream>>>(Wf[4], wpb + WPO_S5, 47, 48, 114, 64, 188, 770048);
    pack_w<<<(1728000 + 255) / 256, 256, 0, stream>>>(Wf[6], wpb + WPO_S7, 96, 96, 144, 48, 375, 1728000);
    pack_w_lds2<<<(98304 + 255) / 256, 256, 0, stream>>>(Wf[1], wpb + WPO_S2, 20, 24, 32, 3, 98304);
    pack_w_lds2<<<(393216 + 255) / 256, 256, 0, stream>>>(Wf[3], wpb + WPO_S4, 47, 56, 64, 6, 393216);
    pack_w_lds2<<<(1572864 + 255) / 256, 256, 0, stream>>>(Wf[5], wpb + WPO_S6, 96, 114, 64, 12, 1572864);
    pack_w_lds2<<<(7864320 + 255) / 256, 256, 0, stream>>>(Wf[7], wpb + WPO_S8, 120, 512, 64, 15, 7864320);

    long rows;

    // stage 1 (ig): 64->34 s2, Cout 24, K=1000; act emits CH=24 for s2-lds2
    rows = 628864;
    conv_ig<8, 72, 34, 2, 24, 2, 32, 1000><<<dim3(2457, 1), 256, 0, stream>>>(H, wpb + WPO_S1, yb);
    bn_partial_cl<<<256, 256, 0, stream>>>(yb, part, rows, 24, 5);
    bn_finalize<<<1, 256, 0, stream>>>(part, stats, 24, 1.f / (float)rows);
    act_pad<24, 42, 34><<<111132, 256, 0, stream>>>(yb, stats, H, 24, 20, 6, 3);

    // stage 2 (lds2): 34->38 s1, Cout 24, CH=24 (3 chunks), tile (2,3,38)
    rows = 877952;
    conv_lds2<3, 42, 38, 2, 3, 24, 2, 4><<<dim3(3952, 1), 256, 0, stream>>>(H, wpb + WPO_S2, yb);
    bn_partial_cl<<<256, 256, 0, stream>>>(yb, part, rows, 24, 5);
    bn_finalize<<<1, 256, 0, stream>>>(part, stats, 24, 1.f / (float)rows);
    act_pad<24, 46, 38><<<146004, 256, 0, stream>>>(yb, stats, H, 24, 20, 6, 3);

    // stage 3 (ig): 38->21 s2, Cout 56, K=3000; act emits CH=48 for s4-lds2
    rows = 148176;
    conv_ig<24, 46, 21, 2, 56, 4, 94, 3000><<<dim3(579, 1), 256, 0, stream>>>(H, wpb + WPO_S3, yb);
    bn_partial_cl<<<256, 256, 0, stream>>>(yb, part, rows, 56, 6);
    bn_finalize<<<1, 256, 0, stream>>>(part, stats, 56, 1.f / (float)rows);
    act_pad<48, 29, 21><<<73167, 256, 0, stream>>>(yb, stats, H, 56, 47, 14, 6);

    // stage 4 (lds2): 21->25 s1, Cout 56, CH=48 (6 chunks), tile (2,5,25)
    rows = 250000;
    conv_lds2<6, 29, 25, 2, 5, 56, 4, 4><<<dim3(1040, 1), 256, 0, stream>>>(H, wpb + WPO_S4, yb);
    bn_partial_cl<<<256, 256, 0, stream>>>(yb, part, rows, 56, 6);
    bn_finalize<<<1, 256, 0, stream>>>(part, stats, 56, 1.f / (float)rows);
    act_pad<48, 33, 25><<<107811, 256, 0, stream>>>(yb, stats, H, 56, 47, 14, 6);

    // stage 5 (ig): 25->15 s2, Cout 114, K=6000
    rows = 54000;
    conv_ig<48, 33, 15, 2, 114, 4, 188, 6000><<<dim3(211, 2), 256, 0, stream>>>(H, wpb + WPO_S5, yb);
    bn_partial_cl<<<256, 256, 0, stream>>>(yb, part, rows, 114, 7);
    bn_finalize<<<1, 256, 0, stream>>>(part, stats, 114, 1.f / (float)rows);
    act_pad<96, 23, 15><<<73002, 256, 0, stream>>>(yb, stats, H, 114, 96, 30, 12);

    // stage 6 (lds2): 15->19 s1, Cout 114, CH=96 (12 chunks), tile (2,6,19)
    rows = 109744;
    conv_lds2<12, 23, 19, 2, 6, 114, 4, 4><<<dim3(640, 2), 256, 0, stream>>>(H, wpb + WPO_S6, yb);
    bn_partial_cl<<<256, 256, 0, stream>>>(yb, part, rows, 114, 7);
    bn_finalize<<<1, 256, 0, stream>>>(part, stats, 114, 1.f / (float)rows);
    act_pad<96, 27, 19><<<118098, 256, 0, stream>>>(yb, stats, H, 114, 96, 30, 12);

    // stage 7 (ig): 19->12 s2, Cout 144, K=12000; act emits CH=120 for s8-lds2
    rows = 27648;
    conv_ig<96, 27, 12, 2, 144, 3, 375, 12000><<<dim3(108, 3), 256, 0, stream>>>(H, wpb + WPO_S7, yb);
    bn_partial_cl<<<256, 256, 0, stream>>>(yb, part, rows, 144, 8);
    bn_finalize<<<1, 256, 0, stream>>>(part, stats, 144, 1.f / (float)rows);
    act_pad<120, 20, 12><<<60000, 256, 0, stream>>>(yb, stats, H, 144, 120, 32, 16);

    // stage 8 (lds2): 12->16 s1, Cout 512 in ONE dispatch, CH=120 (15 chunks),
    // tile (4,4,16), grid (256,8) = 2048 blocks; patch = 20480 B -> 8 blocks/CU
    rows = 65536;
    conv_lds2<15, 20, 16, 4, 4, 512, 4, 4><<<dim3(256, 8), 256, 0, stream>>>(
        H, wpb + WPO_S8, yb);
    bn_partial512<<<256, 256, 0, stream>>>(yb, part, rows);
    bn_finalize512<<<2, 256, 0, stream>>>(part, stats, 1.f / (float)rows);
    pool_partial512<<<dim3(16, 64), 256, 0, stream>>>(yb, stats, pp);
    pool_final512<<<16, 256, 0, stream>>>(pp, pooled);
    linear20<<<dim3(20, 16), 64, 0, stream>>>(pooled, linW, linb, out);
}

// Round 15
// 3502.407 us; speedup vs baseline: 1.2559x; 1.2559x over previous
//
#include <hip/hip_runtime.h>
#include <hip/hip_bf16.h>

typedef __bf16 bf16x8 __attribute__((ext_vector_type(8)));
typedef float f32x4 __attribute__((ext_vector_type(4)));
typedef unsigned int uint4v __attribute__((ext_vector_type(4)));
typedef unsigned short ushortT;
typedef ushortT ushort8v __attribute__((ext_vector_type(8)));

__device__ __forceinline__ ushortT f2b(float f) {
    __bf16 b = (__bf16)f;
    return __builtin_bit_cast(ushortT, b);
}

// bijective chunked XCD swizzle (m204)
__device__ __forceinline__ unsigned xcd_swz(unsigned bx, unsigned nwg) {
    unsigned q = nwg >> 3, r = nwg & 7, xcd = bx & 7, off = bx >> 3;
    return (xcd < r ? xcd * (q + 1) : r * (q + 1) + (xcd - r) * q) + off;
}

// ---------------- input pack: fp32 [16][7][64^3] -> halo-padded bf16 ----------
__global__ __launch_bounds__(256) void pack_x(const float* __restrict__ x,
                                              ushortT* __restrict__ xb)
{
    long e = (long)blockIdx.x * 256 + threadIdx.x;   // 16*72^3 = 5,971,968
    if (e >= 5971968L) return;
    int wp_ = (int)(e % 72); long r = e / 72;
    int hp = (int)(r % 72); r /= 72;
    int dp = (int)(r % 72); int b = (int)(r / 72);
    ushort8v v = (ushort8v)0;
    int dd = dp - 4, hh = hp - 4, ww = wp_ - 4;
    if ((unsigned)dd < 64u && (unsigned)hh < 64u && (unsigned)ww < 64u) {
        int sp = (dd * 64 + hh) * 64 + ww;
        #pragma unroll
        for (int c = 0; c < 7; ++c)
            v[c] = f2b(x[((size_t)(b * 7 + c)) * 262144 + sp]);
    }
    *(ushort8v*)(xb + e * 8) = v;
}

// ---------------- weight pack (conv_ig layout): [NBY][KSTEPS][4][NW][8] -------
__global__ void pack_w(const float* __restrict__ W, ushortT* __restrict__ wp,
                       int Cin, int CINP, int Cout, int NW, int KSTEPS, int total)
{
    int e = blockIdx.x * 256 + threadIdx.x;
    if (e >= total) return;
    int j = e & 7;
    int r = e >> 3;
    int c = r % NW; r /= NW;
    int q = r & 3; r >>= 2;
    int s = r % KSTEPS;
    int nby = r / KSTEPS;
    int k = s * 32 + q * 8 + j;
    int tap = k / CINP;
    int ci = k - tap * CINP;
    int n = nby * NW + c;
    float v = 0.f;
    if (tap < 125 && ci < Cin && n < Cout)
        v = W[((size_t)n * Cin + ci) * 125 + tap];
    wp[e] = f2b(v);
}

// ---- weight pack (conv_lds2 layout): [NBY][CHUNKS][32 s][4 q][NW][8 j] ------
// k-mapping: tap = 4s + q; ci = c*8 + j
__global__ void pack_w_lds2(const float* __restrict__ W, ushortT* __restrict__ wp,
                            int Cin, int Cout, int NW, int CHUNKS, int total)
{
    int e = blockIdx.x * 256 + threadIdx.x;
    if (e >= total) return;
    int j = e & 7;
    int r = e >> 3;
    int n = r % NW; r /= NW;
    int q = r & 3; r >>= 2;
    int s = r % 32; r /= 32;
    int c = r % CHUNKS;
    int nby = r / CHUNKS;
    int tap = 4 * s + q;
    int ci = c * 8 + j;
    int nn = nby * NW + n;
    float v = 0.f;
    if (tap < 125 && ci < Cin && nn < Cout)
        v = W[((size_t)nn * Cin + ci) * 125 + tap];
    wp[e] = f2b(v);
}

// ---------------- implicit-GEMM conv, direct global A (stride-2 stages) ------
template<int CINP, int INDP, int OUTD, int STRIDE, int COUT, int NFRAG, int KSTEPS, int KTOT>
__global__ __launch_bounds__(256)
void conv_ig(const ushortT* __restrict__ xcl, const ushortT* __restrict__ wp,
             float* __restrict__ y)
{
    constexpr int S3 = OUTD * OUTD * OUTD;
    constexpr long MTOT = 16L * S3;
    constexpr int NW = NFRAG * 16;
    const int t = threadIdx.x, lane = t & 63, wave = t >> 6;
    const unsigned bx = xcd_swz(blockIdx.x, gridDim.x);
    const long mbase = (long)bx * 256 + wave * 64;
    const int slot = lane >> 4;

    unsigned rb[4];
    #pragma unroll
    for (int i = 0; i < 4; ++i) {
        long m = mbase + i * 16 + (lane & 15);
        if (m >= MTOT) m = MTOT - 1;
        int b = (int)(m / S3); int sp = (int)(m % S3);
        int od = sp / (OUTD * OUTD); int oh = (sp / OUTD) % OUTD; int ow = sp % OUTD;
        rb[i] = (unsigned)(((((b * INDP) + od * STRIDE) * INDP + oh * STRIDE) * INDP
                            + ow * STRIDE) * CINP);
    }
    const ushortT* wptr = wp + ((size_t)((blockIdx.y * KSTEPS) * 4 + slot) * NW
                                + (lane & 15)) * 8;

    f32x4 acc[NFRAG][4];
    #pragma unroll
    for (int n = 0; n < NFRAG; ++n)
        #pragma unroll
        for (int i = 0; i < 4; ++i) acc[n][i] = (f32x4)0.f;

    for (int s = 0; s < KSTEPS; ++s) {
        const int k0 = s * 32 + slot * 8;
        const int tap = k0 / CINP;
        const int ci = k0 - tap * CINP;
        const int kd = tap / 25;
        const int rr = tap - kd * 25;
        const int kh = rr / 5;
        const int kw = rr - kh * 5;
        const unsigned toff = (unsigned)(((kd * INDP + kh) * INDP + kw) * CINP + ci);
        const bool valid = k0 < KTOT;
        uint4v a[4];
        #pragma unroll
        for (int i = 0; i < 4; ++i) {
            unsigned idx = valid ? (rb[i] + toff) : 0u;
            a[i] = *(const uint4v*)(xcl + idx);
        }
        uint4v bv[NFRAG];
        #pragma unroll
        for (int n = 0; n < NFRAG; ++n)
            bv[n] = *(const uint4v*)(wptr + (size_t)s * (4 * NW * 8) + n * 128);
        #pragma unroll
        for (int n = 0; n < NFRAG; ++n) {
            bf16x8 bb = __builtin_bit_cast(bf16x8, bv[n]);
            #pragma unroll
            for (int i = 0; i < 4; ++i)
                acc[n][i] = __builtin_amdgcn_mfma_f32_16x16x32_bf16(
                    __builtin_bit_cast(bf16x8, a[i]), bb, acc[n][i], 0, 0, 0);
        }
    }

    const int rbase = (lane >> 4) * 4;
    #pragma unroll
    for (int n = 0; n < NFRAG; ++n) {
        int nn = blockIdx.y * NW + n * 16 + (lane & 15);
        if (nn >= COUT) continue;
        #pragma unroll
        for (int i = 0; i < 4; ++i) {
            #pragma unroll
            for (int r = 0; r < 4; ++r) {
                long mm = mbase + i * 16 + rbase + r;
                if (mm < MTOT) y[(size_t)mm * COUT + nn] = acc[n][i][r];
            }
        }
    }
}

// --------- LDS-patch implicit-GEMM conv v2: 8-ch chunks for occupancy --------
// patch layout [pos][8ch] = 16B/pos; K-step = 4 taps x 8 ch; 32 steps/chunk.
// FROZEN (r10-r14): every perturbation of this inner loop (cross-barrier
// prefetch, unroll, setprio, addr precompute, arithmetic toff) regressed via
// VGPR/occupancy. The LDS tofftab + 56-VGPR schedule is the local optimum.
template<int CHUNKS, int INDP, int OUTD, int TD, int TH, int COUT, int NFRAG, int MFRAG>
__global__ __launch_bounds__(256)
void conv_lds2(const ushortT* __restrict__ xcl, const ushortT* __restrict__ wp,
               float* __restrict__ y)
{
    constexpr int CH = CHUNKS * 8;
    constexpr int PD = TD + 4, PH = TH + 4, PW = INDP;
    constexpr int P3 = PD * PH * PW;
    constexpr int ROWS = TD * TH * OUTD;
    constexpr int NW = NFRAG * 16;
    constexpr int NTD = (OUTD + TD - 1) / TD;
    constexpr int NTH = (OUTD + TH - 1) / TH;
    constexpr size_t PERNBY = (size_t)CHUNKS * 32 * 4 * NW * 8;
    static_assert(ROWS <= MFRAG * 64, "row coverage");

    __shared__ __align__(16) ushortT patch[P3 * 8];
    __shared__ int tofftab[128];

    const int t = threadIdx.x, lane = t & 63, wave = t >> 6;
    const unsigned bt = xcd_swz(blockIdx.x, gridDim.x);
    const int img = bt / (NTD * NTH);
    const int t2 = bt % (NTD * NTH);
    const int od0 = (t2 / NTH) * TD;
    const int oh0 = (t2 % NTH) * TH;

    if (t < 128) {
        int tap = t < 125 ? t : 0;   // pad taps -> pos 0 (weights are 0)
        int kd = tap / 25, rr = tap - kd * 25, kh = rr / 5, kw = rr - kh * 5;
        tofftab[t] = (t < 125) ? ((kd * PH + kh) * PW + kw) : 0;
    }

    const int r16 = lane & 15, q = lane >> 4;

    int rb[MFRAG];
    #pragma unroll
    for (int i = 0; i < MFRAG; ++i) {
        int r = wave * (MFRAG * 16) + i * 16 + r16;
        if (r >= ROWS) r = ROWS - 1;
        int td = r / (TH * OUTD); int rem = r - td * (TH * OUTD);
        int th = rem / OUTD; int ow = rem - th * OUTD;
        rb[i] = (td * PH + th) * PW + ow;
    }

    const ushortT* wb = wp + (size_t)blockIdx.y * PERNBY + ((size_t)q * NW + r16) * 8;
    const ushortT* src0 = xcl + (size_t)img * INDP * INDP * INDP * CH;

    f32x4 acc[NFRAG][MFRAG];
    #pragma unroll
    for (int n = 0; n < NFRAG; ++n)
        #pragma unroll
        for (int i = 0; i < MFRAG; ++i) acc[n][i] = (f32x4)0.f;

    for (int c = 0; c < CHUNKS; ++c) {
        __syncthreads();                      // prior chunk's patch reads done
        for (int u = t; u < P3; u += 256) {
            int pd = u / (PH * PW); int pr = u - pd * (PH * PW);
            int ph = pr / PW; int pw = pr - ph * PW;
            int gd = od0 + pd; if (gd > INDP - 1) gd = INDP - 1;
            int gh = oh0 + ph; if (gh > INDP - 1) gh = INDP - 1;
            const ushortT* sp_ = src0 + (((size_t)gd * INDP + gh) * INDP + pw) * CH
                                 + c * 8;
            uint4v v = *(const uint4v*)sp_;
            *(uint4v*)&patch[u * 8] = v;
        }
        __syncthreads();                      // patch ready
        const ushortT* wc = wb + (size_t)c * (32 * 4 * NW * 8);
        for (int s = 0; s < 32; ++s) {
            int toffv = tofftab[4 * s + q];
            uint4v bv[NFRAG];
            #pragma unroll
            for (int n = 0; n < NFRAG; ++n)
                bv[n] = *(const uint4v*)(wc + (size_t)s * (4 * NW * 8) + n * 128);
            #pragma unroll
            for (int i = 0; i < MFRAG; ++i) {
                bf16x8 av = *(const bf16x8*)&patch[(rb[i] + toffv) * 8];
                #pragma unroll
                for (int n = 0; n < NFRAG; ++n)
                    acc[n][i] = __builtin_amdgcn_mfma_f32_16x16x32_bf16(
                        av, __builtin_bit_cast(bf16x8, bv[n]), acc[n][i], 0, 0, 0);
            }
        }
    }

    // epilogue: D map col = r16 (n), row = q*4 + reg (m within 16)
    #pragma unroll
    for (int i = 0; i < MFRAG; ++i) {
        #pragma unroll
        for (int vr = 0; vr < 4; ++vr) {
            int r = wave * (MFRAG * 16) + i * 16 + q * 4 + vr;
            if (r >= ROWS) continue;
            int td = r / (TH * OUTD); int rem = r - td * (TH * OUTD);
            int th = rem / OUTD; int ow = rem - th * OUTD;
            int od = od0 + td, oh = oh0 + th;
            if (od >= OUTD || oh >= OUTD) continue;
            size_t row = ((size_t)img * OUTD + od) * (size_t)(OUTD * OUTD)
                       + (size_t)oh * OUTD + ow;
            #pragma unroll
            for (int n = 0; n < NFRAG; ++n) {
                int nn = blockIdx.y * NW + n * 16 + r16;
                if (nn < COUT) y[row * COUT + nn] = acc[n][i][vr];
            }
        }
    }
}

// ---------------- BN partial sums over y [rows][C], C<=256 ----------------
__global__ __launch_bounds__(256)
void bn_partial_cl(const float* __restrict__ y, float* __restrict__ part,
                   long rows, int C, int crlog2)
{
    const int t = threadIdx.x;
    const int CR = 1 << crlog2;
    const int c = t & (CR - 1);
    const int r0 = t >> crlog2;
    const int rstep = 256 >> crlog2;
    float s0 = 0.f, q0 = 0.f;
    const bool has = c < C;
    for (long r = (long)blockIdx.x * rstep + r0; r < rows; r += 256L * rstep) {
        if (has) { float v = y[(size_t)r * C + c]; s0 += v; q0 = fmaf(v, v, q0); }
    }
    __shared__ float l0[256], l1[256];
    l0[t] = s0; l1[t] = q0; __syncthreads();
    if (t < CR) {
        for (int j = 1; j < rstep; ++j) { s0 += l0[t + j * CR]; q0 += l1[t + j * CR]; }
        if (t < C) {
            part[((size_t)blockIdx.x * 256 + t) * 2]     = s0;
            part[((size_t)blockIdx.x * 256 + t) * 2 + 1] = q0;
        }
    }
}

__global__ void bn_finalize(const float* __restrict__ part, float* __restrict__ stats,
                            int C, float invN)
{
    int c = threadIdx.x;
    if (c >= C) return;
    float s = 0.f, q = 0.f;
    for (int k = 0; k < 256; ++k) {
        s += part[((size_t)k * 256 + c) * 2];
        q += part[((size_t)k * 256 + c) * 2 + 1];
    }
    float mean = s * invN;
    float var = q * invN - mean * mean;
    stats[2 * c] = mean;
    stats[2 * c + 1] = rsqrtf(var + 1e-5f);
}

// ---------------- BN for C=512 (stage 8), y [rows][512] ----------------
__global__ __launch_bounds__(256)
void bn_partial512(const float* __restrict__ y, float* __restrict__ part, long rows)
{
    const int t = threadIdx.x;
    float s0 = 0.f, q0 = 0.f, s1 = 0.f, q1 = 0.f;
    for (long r = blockIdx.x; r < rows; r += 256) {
        const float* row = y + (size_t)r * 512;
        float v0 = row[t];       s0 += v0; q0 = fmaf(v0, v0, q0);
        float v1 = row[t + 256]; s1 += v1; q1 = fmaf(v1, v1, q1);
    }
    part[((size_t)blockIdx.x * 512 + t) * 2]           = s0;
    part[((size_t)blockIdx.x * 512 + t) * 2 + 1]       = q0;
    part[((size_t)blockIdx.x * 512 + t + 256) * 2]     = s1;
    part[((size_t)blockIdx.x * 512 + t + 256) * 2 + 1] = q1;
}

__global__ void bn_finalize512(const float* __restrict__ part, float* __restrict__ stats,
                               float invN)
{
    int c = blockIdx.x * 256 + threadIdx.x;   // grid 2 x 256
    float s = 0.f, q = 0.f;
    for (int k = 0; k < 256; ++k) {
        s += part[((size_t)k * 512 + c) * 2];
        q += part[((size_t)k * 512 + c) * 2 + 1];
    }
    float mean = s * invN;
    float var = q * invN - mean * mean;
    stats[2 * c] = mean;
    stats[2 * c + 1] = rsqrtf(var + 1e-5f);
}

// ---------------- normalize + gate -> halo-padded bf16 for next stage --------
template<int CINP, int INDP, int OUTD>
__global__ __launch_bounds__(256)
void act_pad(const float* __restrict__ y, const float* __restrict__ stats,
             ushortT* __restrict__ h, int COUT, int d, int m0, int m1)
{
    constexpr long TOT = 16L * INDP * INDP * INDP * CINP;
    long e = (long)blockIdx.x * 256 + threadIdx.x;
    if (e >= TOT) return;
    int c = (int)(e % CINP); long r = e / CINP;
    int wp_ = (int)(r % INDP); r /= INDP;
    int hp = (int)(r % INDP); r /= INDP;
    int dp = (int)(r % INDP); int b = (int)(r / INDP);
    float o = 0.f;
    int dd = dp - 4, hh = hp - 4, ww = wp_ - 4;
    if (c < d && (unsigned)dd < (unsigned)OUTD && (unsigned)hh < (unsigned)OUTD
        && (unsigned)ww < (unsigned)OUTD) {
        long row = ((b * (long)OUTD + dd) * OUTD + hh) * OUTD + ww;
        float v = (y[row * COUT + c] - stats[2 * c]) * stats[2 * c + 1];
        if (c < m0) {
            o = fmaxf(v, 0.f);
        } else {
            int gi = (c < m0 + 3 * m1) ? (d + (c - m0) / 3)
                                       : (d + m1 + (c - m0 - 3 * m1) / 5);
            float g = (y[row * COUT + gi] - stats[2 * gi]) * stats[2 * gi + 1];
            o = v / (1.f + __expf(-g));
        }
    }
    h[e] = f2b(o);
}

// ---------------- stage-8 pooling over y [16][4096][512] ----------------
__global__ __launch_bounds__(256)
void pool_partial512(const float* __restrict__ y, const float* __restrict__ stats,
                     float* __restrict__ pp)
{
    const int b = blockIdx.x, slab = blockIdx.y, t = threadIdx.x;
    const int c0 = t, c1 = t + 256;
    const float mu0 = stats[2 * c0], iv0 = stats[2 * c0 + 1];
    const float mu1 = stats[2 * c1], iv1 = stats[2 * c1 + 1];
    float a0 = 0.f, a1 = 0.f;
    for (int i = 0; i < 64; ++i) {
        const float* row = y + ((size_t)b * 4096 + slab * 64 + i) * 512;
        a0 += fmaxf((row[c0] - mu0) * iv0, 0.f);
        a1 += fmaxf((row[c1] - mu1) * iv1, 0.f);
    }
    pp[(size_t)(b * 64 + slab) * 512 + c0] = a0;
    pp[(size_t)(b * 64 + slab) * 512 + c1] = a1;
}

__global__ void pool_final512(const float* __restrict__ pp, float* __restrict__ pooled)
{
    const int b = blockIdx.x, t = threadIdx.x;
    float a0 = 0.f, a1 = 0.f;
    for (int s = 0; s < 64; ++s) {
        a0 += pp[(size_t)(b * 64 + s) * 512 + t];
        a1 += pp[(size_t)(b * 64 + s) * 512 + t + 256];
    }
    pooled[b * 512 + t]       = a0 * (1.f / 4096.f);
    pooled[b * 512 + t + 256] = a1 * (1.f / 4096.f);
}

// ---------------- final linear ----------------
__global__ void linear20(const float* __restrict__ pooled, const float* __restrict__ lw,
                         const float* __restrict__ lb, float* __restrict__ out)
{
    const int n = blockIdx.x, b = blockIdx.y;
    const float* p = pooled + b * 512;
    const float* w = lw + n * 512;
    float s = 0.f;
    for (int c = threadIdx.x; c < 512; c += 64) s = fmaf(p[c], w[c], s);
    for (int o = 32; o > 0; o >>= 1) s += __shfl_down(s, o);
    if (threadIdx.x == 0) out[b * 20 + n] = s + lb[n];
}

// ---------------- host ----------------
extern "C" void kernel_launch(void* const* d_in, const int* in_sizes, int n_in,
                              void* d_out, int out_size, void* d_ws, size_t ws_size,
                              hipStream_t stream) {
    const float* x = (const float*)d_in[0];
    const float* Wf[8];
    for (int i = 0; i < 8; ++i) Wf[i] = (const float*)d_in[1 + i];
    const float* linW = (const float*)d_in[9];
    const float* linb = (const float*)d_in[10];
    float* out = (float*)d_out;
    float* ws = (float*)d_ws;

    // workspace layout (float units)
    const size_t OFF_Y    = 0;            // 33,554,432 f (max y: s8 65536x512)
    const size_t OFF_H    = 33554432;     // 23,887,872 f (bf16)
    const size_t OFF_WP   = 57442304;     //  6,326,016 f (bf16)
    const size_t OFF_PART = 63768320;     //    262,144 f
    const size_t OFF_PP   = 64030464;     //    524,288 f
    const size_t OFF_ST   = 64554752;     //      1,024 f
    const size_t OFF_PL   = 64555776;     //      8,192 f
    const size_t NEEDF    = 64563968;     // ~258.3 MB
    if (ws_size < NEEDF * sizeof(float)) return;

    float* yb = ws + OFF_Y;
    ushortT* H = (ushortT*)(ws + OFF_H);
    ushortT* wpb = (ushortT*)(ws + OFF_WP);
    float* part = ws + OFF_PART;
    float* pp = ws + OFF_PP;
    float* stats = ws + OFF_ST;
    float* pooled = ws + OFF_PL;

    // packed-weight offsets (ushort units)
    const size_t WPO_S1 = 0;          // ig:   32*4*32*8       = 32,768
    const size_t WPO_S3 = 32768;      // ig:   94*4*64*8       = 192,512
    const size_t WPO_S5 = 225280;     // ig:   2*188*4*64*8    = 770,048
    const size_t WPO_S7 = 995328;     // ig:   3*375*4*48*8    = 1,728,000
    const size_t WPO_S2 = 2723328;    // lds2: 1*3*32*4*32*8   = 98,304
    const size_t WPO_S4 = 2821632;    // lds2: 1*6*32*4*64*8   = 393,216
    const size_t WPO_S6 = 3214848;    // lds2: 2*12*32*4*64*8  = 1,572,864
    const size_t WPO_S8 = 4787712;    // lds2: 8*15*32*4*64*8  = 7,864,320

    pack_x<<<23328, 256, 0, stream>>>(x, H);
    pack_w<<<(32768 + 255) / 256, 256, 0, stream>>>(Wf[0], wpb + WPO_S1, 7, 8, 24, 32, 32, 32768);
    pack_w<<<(192512 + 255) / 256, 256, 0, stream>>>(Wf[2], wpb + WPO_S3, 20, 24, 56, 64, 94, 192512);
    pack_w<<<(770048 + 255) / 256, 256, 0, stream>>>(Wf[4], wpb + WPO_S5, 47, 48, 114, 64, 188, 770048);
    pack_w<<<(1728000 + 255) / 256, 256, 0, stream>>>(Wf[6], wpb + WPO_S7, 96, 96, 144, 48, 375, 1728000);
    pack_w_lds2<<<(98304 + 255) / 256, 256, 0, stream>>>(Wf[1], wpb + WPO_S2, 20, 24, 32, 3, 98304);
    pack_w_lds2<<<(393216 + 255) / 256, 256, 0, stream>>>(Wf[3], wpb + WPO_S4, 47, 56, 64, 6, 393216);
    pack_w_lds2<<<(1572864 + 255) / 256, 256, 0, stream>>>(Wf[5], wpb + WPO_S6, 96, 114, 64, 12, 1572864);
    pack_w_lds2<<<(7864320 + 255) / 256, 256, 0, stream>>>(Wf[7], wpb + WPO_S8, 120, 512, 64, 15, 7864320);

    long rows;

    // stage 1 (ig): 64->34 s2, Cout 24, K=1000; act emits CH=24 for s2-lds2
    rows = 628864;
    conv_ig<8, 72, 34, 2, 24, 2, 32, 1000><<<dim3(2457, 1), 256, 0, stream>>>(H, wpb + WPO_S1, yb);
    bn_partial_cl<<<256, 256, 0, stream>>>(yb, part, rows, 24, 5);
    bn_finalize<<<1, 256, 0, stream>>>(part, stats, 24, 1.f / (float)rows);
    act_pad<24, 42, 34><<<111132, 256, 0, stream>>>(yb, stats, H, 24, 20, 6, 3);

    // stage 2 (lds2): 34->38 s1, Cout 24, CH=24 (3 chunks), tile (2,3,38)
    rows = 877952;
    conv_lds2<3, 42, 38, 2, 3, 24, 2, 4><<<dim3(3952, 1), 256, 0, stream>>>(H, wpb + WPO_S2, yb);
    bn_partial_cl<<<256, 256, 0, stream>>>(yb, part, rows, 24, 5);
    bn_finalize<<<1, 256, 0, stream>>>(part, stats, 24, 1.f / (float)rows);
    act_pad<24, 46, 38><<<146004, 256, 0, stream>>>(yb, stats, H, 24, 20, 6, 3);

    // stage 3 (ig): 38->21 s2, Cout 56, K=3000; act emits CH=48 for s4-lds2
    rows = 148176;
    conv_ig<24, 46, 21, 2, 56, 4, 94, 3000><<<dim3(579, 1), 256, 0, stream>>>(H, wpb + WPO_S3, yb);
    bn_partial_cl<<<256, 256, 0, stream>>>(yb, part, rows, 56, 6);
    bn_finalize<<<1, 256, 0, stream>>>(part, stats, 56, 1.f / (float)rows);
    act_pad<48, 29, 21><<<73167, 256, 0, stream>>>(yb, stats, H, 56, 47, 14, 6);

    // stage 4 (lds2): 21->25 s1, Cout 56, CH=48 (6 chunks), tile (2,5,25)
    rows = 250000;
    conv_lds2<6, 29, 25, 2, 5, 56, 4, 4><<<dim3(1040, 1), 256, 0, stream>>>(H, wpb + WPO_S4, yb);
    bn_partial_cl<<<256, 256, 0, stream>>>(yb, part, rows, 56, 6);
    bn_finalize<<<1, 256, 0, stream>>>(part, stats, 56, 1.f / (float)rows);
    act_pad<48, 33, 25><<<107811, 256, 0, stream>>>(yb, stats, H, 56, 47, 14, 6);

    // stage 5 (ig): 25->15 s2, Cout 114, K=6000
    rows = 54000;
    conv_ig<48, 33, 15, 2, 114, 4, 188, 6000><<<dim3(211, 2), 256, 0, stream>>>(H, wpb + WPO_S5, yb);
    bn_partial_cl<<<256, 256, 0, stream>>>(yb, part, rows, 114, 7);
    bn_finalize<<<1, 256, 0, stream>>>(part, stats, 114, 1.f / (float)rows);
    act_pad<96, 23, 15><<<73002, 256, 0, stream>>>(yb, stats, H, 114, 96, 30, 12);

    // stage 6 (lds2): 15->19 s1, Cout 114, CH=96 (12 chunks), tile (2,6,19)
    rows = 109744;
    conv_lds2<12, 23, 19, 2, 6, 114, 4, 4><<<dim3(640, 2), 256, 0, stream>>>(H, wpb + WPO_S6, yb);
    bn_partial_cl<<<256, 256, 0, stream>>>(yb, part, rows, 114, 7);
    bn_finalize<<<1, 256, 0, stream>>>(part, stats, 114, 1.f / (float)rows);
    act_pad<96, 27, 19><<<118098, 256, 0, stream>>>(yb, stats, H, 114, 96, 30, 12);

    // stage 7 (ig): 19->12 s2, Cout 144, K=12000; act emits CH=120 for s8-lds2
    rows = 27648;
    conv_ig<96, 27, 12, 2, 144, 3, 375, 12000><<<dim3(108, 3), 256, 0, stream>>>(H, wpb + WPO_S7, yb);
    bn_partial_cl<<<256, 256, 0, stream>>>(yb, part, rows, 144, 8);
    bn_finalize<<<1, 256, 0, stream>>>(part, stats, 144, 1.f / (float)rows);
    act_pad<120, 20, 12><<<60000, 256, 0, stream>>>(yb, stats, H, 144, 120, 32, 16);

    // stage 8 (lds2): 12->16 s1, Cout 512 in ONE dispatch, CH=120 (15 chunks),
    // tile (4,4,16), grid (256,8) = 2048 blocks
    rows = 65536;
    conv_lds2<15, 20, 16, 4, 4, 512, 4, 4><<<dim3(256, 8), 256, 0, stream>>>(
        H, wpb + WPO_S8, yb);
    bn_partial512<<<256, 256, 0, stream>>>(yb, part, rows);
    bn_finalize512<<<2, 256, 0, stream>>>(part, stats, 1.f / (float)rows);
    pool_partial512<<<dim3(16, 64), 256, 0, stream>>>(yb, stats, pp);
    pool_final512<<<16, 256, 0, stream>>>(pp, pooled);
    linear20<<<dim3(20, 16), 64, 0, stream>>>(pooled, linW, linb, out);
}